// Round 5
// baseline (167.936 us; speedup 1.0000x reference)
//
#include <hip/hip_runtime.h>
#include <stdint.h>

// Problem constants
#define ROWS  16384   // B*T = 512*32
#define CELL  128
#define INF   512
#define RPB   32      // rows per block (2 x 16-row groups per wave)
#define NSTEP 32

typedef _Float16 f16x8 __attribute__((ext_vector_type(8)));
typedef _Float16 f16x4 __attribute__((ext_vector_type(4)));
typedef float    f32x4 __attribute__((ext_vector_type(4)));

#define MFMA16(a, b, c) __builtin_amdgcn_mfma_f32_16x16x32_f16((a), (b), (c), 0, 0, 0)

// ws layout (f16 elems), all in 16x16x32 fragment order (A and B frag layouts
// are identical on gfx950: element dim = lane&15, k = (lane>>4)*8 + j):
//   A_sw[g]  at g*16384          (g=0..3: Wf,Wi1,Wi2,Wo rows 0..127, cell part)
//   Xw_sw[g] at 65536 + g*65536  (rows 128..639, x part)
//   Wc_sw    at 327680
// frag addr: ((ks*8 + nb)*64 + lane)*8 + j  <->
//   W[ks*32 + ((lane>>4)<<3) + j][nb*16 + (lane&15)]
// Weights PRE-SCALED: Wf,Wi1,Wo by log2(e); Wi2 by 2*log2(e); Wc by log2(e).
#define AOFF  0
#define XOFF  65536
#define WCOFF 327680
#define WSTOT 344064

#define LOG2E  1.44269504f
#define LOG2E2 2.88539008f

__device__ __forceinline__ unsigned short f2h_bits(float f) {
  _Float16 h = (_Float16)f;
  return *(unsigned short*)&h;
}
// z pre-scaled by log2e: sigmoid(z_real) = 1/(1+2^(-z))
__device__ __forceinline__ float sig2(float z) {
  return __builtin_amdgcn_rcpf(1.f + __builtin_amdgcn_exp2f(-z));
}
// z pre-scaled by 2*log2e: tanh(z_real) = 1 - 2/(2^z + 1)
__device__ __forceinline__ float tanh2(float z) {
  return 1.f - 2.f * __builtin_amdgcn_rcpf(__builtin_amdgcn_exp2f(z) + 1.f);
}

__global__ __launch_bounds__(256) void prep_kernel(
    const float* __restrict__ Wf, const float* __restrict__ Wi1,
    const float* __restrict__ Wi2, const float* __restrict__ Wo,
    const float* __restrict__ Wc, unsigned short* __restrict__ ws) {
  int id = blockIdx.x * blockDim.x + threadIdx.x;
  if (id >= WSTOT) return;
  const float* Wg[4] = {Wf, Wi1, Wi2, Wo};
  const float scl[4] = {LOG2E, LOG2E, LOG2E2, LOG2E};
  float v;
  int k, n, base;
  if (id < XOFF) {                       // recurrent (cell) part, k = 0..127
    int g = id >> 14, r = id & 16383;
    k = r >> 7; n = r & 127;
    v = Wg[g][k * CELL + n] * scl[g];
    base = g * 16384;
  } else if (id < WCOFF) {               // x part, k = 0..511 -> W row 128+k
    int t = id - XOFF;
    int g = t >> 16, r = t & 65535;
    k = r >> 7; n = r & 127;
    v = Wg[g][(CELL + k) * CELL + n] * scl[g];
    base = XOFF + g * 65536;
  } else {                               // Wc [128][128], scaled by log2e
    int r = id - WCOFF;
    k = r >> 7; n = r & 127;
    v = Wc[k * CELL + n] * LOG2E;
    base = WCOFF;
  }
  int ks = k >> 5, kk = k & 31;
  int lane = ((kk >> 3) << 4) | (n & 15);
  int j = kk & 7, nb = n >> 4;
  ws[base + ((ks * 8 + nb) * 64 + lane) * 8 + j] = f2h_bits(v);
}

// 32 rows/block, 8 waves. Each wave owns 16 cols but TWO 16-row groups
// (h = 0,1), reusing the same 48-VGPR recurrent weight set: 24 MFMA
// (6 independent chains) + 48 trans per step per wave, ONE barrier per
// step amortized over 2x work. Grid = 512 = exactly 2 blocks/CU, fully
// resident in one round. u for the o-gate lives in LDS (reloaded at the
// final step) to keep total regs <= 128 (4 waves/SIMD).
__global__ __launch_bounds__(512, 4) void lstm_kernel(
    const float* __restrict__ x,
    const float* __restrict__ bf_, const float* __restrict__ bi1,
    const float* __restrict__ bi2, const float* __restrict__ bo,
    const float* __restrict__ bc,
    const unsigned short* __restrict__ ws, float* __restrict__ out) {

  __shared__ _Float16 cF[2][32 * 128];       // 16384 B, double-buffered c (swz)
  __shared__ union {
    _Float16 xs[32 * 512];                   // 32768 B, x staging (swz)
    struct {
      float    ue[32][132];                  // 16896 B: u_o (recurrence) / e (epilogue)
      _Float16 o[32 * 128];                  // 8192 B, o activations (swz)
    } ep;                                    // 25088 B
  } uS;                                      // total LDS: 49152 B

  const int tid  = threadIdx.x;
  const int lane = tid & 63;
  const int w    = tid >> 6;     // wave 0..7
  const int n16  = lane & 15;    // batch row within group (output mapping)
  const int g4   = lane >> 4;    // 0..3
  const int sxor = n16 & 7;      // per-row swizzle key ((h*16+n16)&7 == n16&7)
  const int col0 = w * 16 + g4 * 4;  // first of this lane's 4 output columns
  const int r0   = blockIdx.x * RPB;

  const _Float16* Aw  = (const _Float16*)ws + AOFF;
  const _Float16* Xw  = (const _Float16*)ws + XOFF;
  const _Float16* Wcw = (const _Float16*)ws + WCOFF;

  // loop-invariant swizzled fragment offsets (f16 units); h=1 adds 2048
  int aoff[4];
#pragma unroll
  for (int ks = 0; ks < 4; ++ks)
    aoff[ks] = n16 * 128 + (((4 * ks + g4) ^ sxor) << 3);
  const int woff = n16 * 128 + (((2 * w + (g4 >> 1)) ^ sxor) << 3) + (g4 & 1) * 4;

  // ---------------- stage x (32 rows x 512 f32 -> f16, swizzled) ----------
  {
    const float* xb = x + (size_t)r0 * INF;
#pragma unroll
    for (int i = 0; i < 8; ++i) {
      int flat = tid + i * 512;            // 4096 = 32 rows * 128 float4
      int row = flat >> 7, c4 = flat & 127;
      const float4 v = ((const float4*)(xb + (size_t)row * INF))[c4];
      f16x4 h = {(_Float16)v.x, (_Float16)v.y, (_Float16)v.z, (_Float16)v.w};
      int idx = row * 512 + (((c4 >> 1) ^ (row & 7)) << 3) + (c4 & 1) * 4;
      *(f16x4*)&uS.xs[idx] = h;
    }
  }
  __syncthreads();

  // ---------------- u[h][g] = x @ Wg[128:,:] + b --------------------------
  f32x4 u[2][4];
#pragma unroll
  for (int h = 0; h < 2; ++h)
#pragma unroll
    for (int g = 0; g < 4; ++g)
#pragma unroll
      for (int i = 0; i < 4; ++i) u[h][g][i] = 0.f;

#pragma unroll 2
  for (int ks = 0; ks < 16; ++ks) {
    f16x8 b0 = *(const f16x8*)(Xw + 0 * 65536 + ((ks * 8 + w) * 64 + lane) * 8);
    f16x8 b1 = *(const f16x8*)(Xw + 1 * 65536 + ((ks * 8 + w) * 64 + lane) * 8);
    f16x8 b2 = *(const f16x8*)(Xw + 2 * 65536 + ((ks * 8 + w) * 64 + lane) * 8);
    f16x8 b3 = *(const f16x8*)(Xw + 3 * 65536 + ((ks * 8 + w) * 64 + lane) * 8);
#pragma unroll
    for (int h = 0; h < 2; ++h) {
      f16x8 a = *(const f16x8*)&uS.xs[(h * 16 + n16) * 512 +
                                      (((4 * ks + g4) ^ sxor) << 3)];
      u[h][0] = MFMA16(b0, a, u[h][0]);
      u[h][1] = MFMA16(b1, a, u[h][1]);
      u[h][2] = MFMA16(b2, a, u[h][2]);
      u[h][3] = MFMA16(b3, a, u[h][3]);
    }
  }
  {
    f32x4 b0 = *(const f32x4*)&bf_[col0];
    f32x4 b1 = *(const f32x4*)&bi1[col0];
    f32x4 b2 = *(const f32x4*)&bi2[col0];
    f32x4 b3 = *(const f32x4*)&bo[col0];
#pragma unroll
    for (int h = 0; h < 2; ++h)
#pragma unroll
      for (int i = 0; i < 4; ++i) {
        u[h][0][i] = fmaf(b0[i], LOG2E,  u[h][0][i]);
        u[h][1][i] = fmaf(b1[i], LOG2E,  u[h][1][i]);
        u[h][2][i] = fmaf(b2[i], LOG2E2, u[h][2][i]);
        u[h][3][i] = fmaf(b3[i], LOG2E,  u[h][3][i]);
      }
  }
  __syncthreads();   // all xs reads done; ue region becomes safe to write

  // park o-gate preactivation in LDS (frees 8 VGPR for the hot loop)
  *(f32x4*)&uS.ep.ue[n16][col0]      = u[0][3];
  *(f32x4*)&uS.ep.ue[16 + n16][col0] = u[1][3];

  // ---------------- recurrent-gate weights -> registers -------------------
  f16x8 wr[3][4];   // [gate f,i1,i2][ks] -> 48 VGPRs
#pragma unroll
  for (int g = 0; g < 3; ++g)
#pragma unroll
    for (int ks = 0; ks < 4; ++ks)
      wr[g][ks] = *(const f16x8*)(Aw + g * 16384 + ((ks * 8 + w) * 64 + lane) * 8);

  // ---------------- step 0: c_prev = 0 => z = u ---------------------------
  f32x4 cr0, cr1;
  {
    f16x4 hv;
#pragma unroll
    for (int i = 0; i < 4; ++i) {
      float c0 = sig2(u[0][1][i]) * tanh2(u[0][2][i]);
      cr0[i] = c0;
      hv[i] = (_Float16)c0;
    }
    *(f16x4*)&cF[0][woff] = hv;
#pragma unroll
    for (int i = 0; i < 4; ++i) {
      float c0 = sig2(u[1][1][i]) * tanh2(u[1][2][i]);
      cr1[i] = c0;
      hv[i] = (_Float16)c0;
    }
    *(f16x4*)&cF[0][2048 + woff] = hv;
  }
  __syncthreads();

  // ---------------- recurrence: steps 1..30 -------------------------------
#pragma unroll 1
  for (int t = 1; t < NSTEP - 1; ++t) {
    const _Float16* rd = cF[(t + 1) & 1];
    _Float16*       wp = cF[t & 1];
    // h0 fragments
    f16x8 a0 = *(const f16x8*)(rd + aoff[0]);
    f16x8 a1 = *(const f16x8*)(rd + aoff[1]);
    f16x8 a2 = *(const f16x8*)(rd + aoff[2]);
    f16x8 a3 = *(const f16x8*)(rd + aoff[3]);
    f32x4 zf  = MFMA16(wr[0][0], a0, u[0][0]);
    f32x4 zi1 = MFMA16(wr[1][0], a0, u[0][1]);
    f32x4 zi2 = MFMA16(wr[2][0], a0, u[0][2]);
    zf  = MFMA16(wr[0][1], a1, zf);
    zi1 = MFMA16(wr[1][1], a1, zi1);
    zi2 = MFMA16(wr[2][1], a1, zi2);
    zf  = MFMA16(wr[0][2], a2, zf);
    zi1 = MFMA16(wr[1][2], a2, zi1);
    zi2 = MFMA16(wr[2][2], a2, zi2);
    zf  = MFMA16(wr[0][3], a3, zf);
    zi1 = MFMA16(wr[1][3], a3, zi1);
    zi2 = MFMA16(wr[2][3], a3, zi2);
    // h1 fragments issued now; latency hides under h0 gate math
    f16x8 e0 = *(const f16x8*)(rd + 2048 + aoff[0]);
    f16x8 e1 = *(const f16x8*)(rd + 2048 + aoff[1]);
    f16x8 e2 = *(const f16x8*)(rd + 2048 + aoff[2]);
    f16x8 e3 = *(const f16x8*)(rd + 2048 + aoff[3]);
    {
      f16x4 hv;
#pragma unroll
      for (int i = 0; i < 4; ++i) {
        float fg = sig2(zf[i]);
        float ig = sig2(zi1[i]);
        float gg = tanh2(zi2[i]);
        float cn = fmaf(cr0[i], fg, ig * gg);
        cr0[i] = cn;
        hv[i] = (_Float16)cn;
      }
      *(f16x4*)&wp[woff] = hv;
    }
    zf  = MFMA16(wr[0][0], e0, u[1][0]);
    zi1 = MFMA16(wr[1][0], e0, u[1][1]);
    zi2 = MFMA16(wr[2][0], e0, u[1][2]);
    zf  = MFMA16(wr[0][1], e1, zf);
    zi1 = MFMA16(wr[1][1], e1, zi1);
    zi2 = MFMA16(wr[2][1], e1, zi2);
    zf  = MFMA16(wr[0][2], e2, zf);
    zi1 = MFMA16(wr[1][2], e2, zi1);
    zi2 = MFMA16(wr[2][2], e2, zi2);
    zf  = MFMA16(wr[0][3], e3, zf);
    zi1 = MFMA16(wr[1][3], e3, zi1);
    zi2 = MFMA16(wr[2][3], e3, zi2);
    {
      f16x4 hv;
#pragma unroll
      for (int i = 0; i < 4; ++i) {
        float fg = sig2(zf[i]);
        float ig = sig2(zi1[i]);
        float gg = tanh2(zi2[i]);
        float cn = fmaf(cr1[i], fg, ig * gg);
        cr1[i] = cn;
        hv[i] = (_Float16)cn;
      }
      *(f16x4*)&wp[2048 + woff] = hv;
    }
    __syncthreads();
  }

  // ---------------- final step (t=31): + o-gate ---------------------------
  {
    const _Float16* rd = cF[0];            // written at t=30
    f16x8 bo0 = *(const f16x8*)(Aw + 3 * 16384 + ((0 * 8 + w) * 64 + lane) * 8);
    f16x8 bo1 = *(const f16x8*)(Aw + 3 * 16384 + ((1 * 8 + w) * 64 + lane) * 8);
    f16x8 bo2 = *(const f16x8*)(Aw + 3 * 16384 + ((2 * 8 + w) * 64 + lane) * 8);
    f16x8 bo3 = *(const f16x8*)(Aw + 3 * 16384 + ((3 * 8 + w) * 64 + lane) * 8);
#pragma unroll
    for (int h = 0; h < 2; ++h) {
      const int hoff = h * 2048;
      f16x8 a0 = *(const f16x8*)(rd + hoff + aoff[0]);
      f16x8 a1 = *(const f16x8*)(rd + hoff + aoff[1]);
      f16x8 a2 = *(const f16x8*)(rd + hoff + aoff[2]);
      f16x8 a3 = *(const f16x8*)(rd + hoff + aoff[3]);
      f32x4 zos = *(const f32x4*)&uS.ep.ue[h * 16 + n16][col0];
      f32x4 zf  = MFMA16(wr[0][0], a0, u[h][0]);
      f32x4 zi1 = MFMA16(wr[1][0], a0, u[h][1]);
      f32x4 zi2 = MFMA16(wr[2][0], a0, u[h][2]);
      f32x4 zo  = MFMA16(bo0,      a0, zos);
      zf  = MFMA16(wr[0][1], a1, zf);
      zi1 = MFMA16(wr[1][1], a1, zi1);
      zi2 = MFMA16(wr[2][1], a1, zi2);
      zo  = MFMA16(bo1,      a1, zo);
      zf  = MFMA16(wr[0][2], a2, zf);
      zi1 = MFMA16(wr[1][2], a2, zi1);
      zi2 = MFMA16(wr[2][2], a2, zi2);
      zo  = MFMA16(bo2,      a2, zo);
      zf  = MFMA16(wr[0][3], a3, zf);
      zi1 = MFMA16(wr[1][3], a3, zi1);
      zi2 = MFMA16(wr[2][3], a3, zi2);
      zo  = MFMA16(bo3,      a3, zo);
      f16x4 hv;
      f32x4& cr = h ? cr1 : cr0;
#pragma unroll
      for (int i = 0; i < 4; ++i) {
        float fg = sig2(zf[i]);
        float ig = sig2(zi1[i]);
        float gg = tanh2(zi2[i]);
        float cn = fmaf(cr[i], fg, ig * gg);
        cr[i] = cn;
        float ov = sig2(zo[i]) * tanh2(cn * LOG2E2);  // cn unscaled
        hv[i] = (_Float16)ov;
      }
      // ep.o is disjoint from ep.ue and cF -> no barrier needed before write
      *(f16x4*)&uS.ep.o[hoff + woff] = hv;
    }
  }
  __syncthreads();

  // -------- epilogue: e = exp2(o @ Wc_scaled + bc*log2e), softmax ---------
  // |s| small (o in (-1,1), Wc ~ N(0,1/sqrt(128))) => max-free softmax.
  {
    f32x4 s0, s1;
#pragma unroll
    for (int i = 0; i < 4; ++i) { s0[i] = 0.f; s1[i] = 0.f; }
#pragma unroll
    for (int ks = 0; ks < 4; ++ks) {
      f16x8 bW = *(const f16x8*)(Wcw + ((ks * 8 + w) * 64 + lane) * 8);
      f16x8 oa = *(const f16x8*)&uS.ep.o[aoff[ks]];
      f16x8 ob = *(const f16x8*)&uS.ep.o[2048 + aoff[ks]];
      s0 = MFMA16(bW, oa, s0);
      s1 = MFMA16(bW, ob, s1);
    }
    f32x4 bcv = *(const f32x4*)&bc[col0];
    f32x4 ev0, ev1;
#pragma unroll
    for (int i = 0; i < 4; ++i) {
      ev0[i] = __builtin_amdgcn_exp2f(fmaf(bcv[i], LOG2E, s0[i]));
      ev1[i] = __builtin_amdgcn_exp2f(fmaf(bcv[i], LOG2E, s1[i]));
    }
    // ue last read at final-step start; barrier above separates
    *(f32x4*)&uS.ep.ue[n16][col0]      = ev0;
    *(f32x4*)&uS.ep.ue[16 + n16][col0] = ev1;
    __syncthreads();

    // wave w reduces rows w*4 .. w*4+3; lane covers cols {lane, lane+64}
#pragma unroll
    for (int rr = 0; rr < 4; ++rr) {
      int r = w * 4 + rr;
      float e0 = uS.ep.ue[r][lane];
      float e1 = uS.ep.ue[r][lane + 64];
      float sm = e0 + e1;
#pragma unroll
      for (int off = 32; off; off >>= 1) sm += __shfl_xor(sm, off, 64);
      float inv = __builtin_amdgcn_rcpf(sm);
      size_t base = (size_t)(r0 + r) * 128;
      out[base + lane]      = e0 * inv;
      out[base + lane + 64] = e1 * inv;
    }

    // final c (output 1) at offset ROWS*128 — float4 store per lane
    *(f32x4*)&out[(size_t)ROWS * 128 + (size_t)(r0 + n16) * 128 + col0] = cr0;
    *(f32x4*)&out[(size_t)ROWS * 128 + (size_t)(r0 + 16 + n16) * 128 + col0] = cr1;
  }
}

extern "C" void kernel_launch(void* const* d_in, const int* in_sizes, int n_in,
                              void* d_out, int out_size, void* d_ws, size_t ws_size,
                              hipStream_t stream) {
  const float* x   = (const float*)d_in[0];
  const float* Wf  = (const float*)d_in[1];
  const float* bf_ = (const float*)d_in[2];
  const float* Wi1 = (const float*)d_in[3];
  const float* bi1 = (const float*)d_in[4];
  const float* Wi2 = (const float*)d_in[5];
  const float* bi2 = (const float*)d_in[6];
  const float* Wo  = (const float*)d_in[7];
  const float* bo  = (const float*)d_in[8];
  const float* Wc  = (const float*)d_in[9];
  const float* bc  = (const float*)d_in[10];
  unsigned short* ws = (unsigned short*)d_ws;
  float* out = (float*)d_out;

  hipLaunchKernelGGL(prep_kernel, dim3((WSTOT + 255) / 256), dim3(256), 0, stream,
                     Wf, Wi1, Wi2, Wo, Wc, ws);
  hipLaunchKernelGGL(lstm_kernel, dim3(ROWS / RPB), dim3(512), 0, stream,
                     x, bf_, bi1, bi2, bo, bc, ws, out);
}